// Round 3
// baseline (1184.564 us; speedup 1.0000x reference)
//
#include <hip/hip_runtime.h>
#include <stdint.h>

#define T_TOK 8192
#define D_DIM 1024
#define H_DIM 4096
#define NGU   8192          // 2*H interleaved gate/up columns
#define NEXP  8
#define MAX_YT 136          // 2*T/128 + NEXP worst-case M-tiles

typedef float  f32x4   __attribute__((ext_vector_type(4)));
typedef float  f32x16  __attribute__((ext_vector_type(16)));
typedef __bf16 bf16x8  __attribute__((ext_vector_type(8)));
typedef __bf16 bf16x4  __attribute__((ext_vector_type(4)));

__device__ __forceinline__ void gl_lds16(const void* g, void* l) {
  // async global->LDS, 16B/lane; LDS dest = wave-uniform base + lane*16
  __builtin_amdgcn_global_load_lds(
      (__attribute__((address_space(1))) void*)g,
      (__attribute__((address_space(3))) void*)l, 16u, 0, 0u);
}

// ---------------- router (+ fused x->bf16 cast) -----------------------------
__global__ __launch_bounds__(256) void router_kernel(
    const float* __restrict__ x, const float* __restrict__ rw,
    const float* __restrict__ temp, __bf16* __restrict__ xb,
    int* __restrict__ rowtok, float* __restrict__ rowwt,
    int* __restrict__ cnt, float* __restrict__ imp_part,
    float* __restrict__ ent_part)
{
  const int wid  = threadIdx.x >> 6;
  const int lane = threadIdx.x & 63;
  const int t    = blockIdx.x * 4 + wid;   // one wave per token

  float acc[8];
#pragma unroll
  for (int e = 0; e < 8; e++) acc[e] = 0.f;
  const float* xr = x + (size_t)t * D_DIM;
#pragma unroll
  for (int it = 0; it < 4; it++) {
    int d = (it * 64 + lane) * 4;
    float4 v = *(const float4*)(xr + d);
    bf16x4 o;
    o[0] = (__bf16)v.x; o[1] = (__bf16)v.y;
    o[2] = (__bf16)v.z; o[3] = (__bf16)v.w;
    *(bf16x4*)(xb + (size_t)t * D_DIM + d) = o;
    float vv[4] = {v.x, v.y, v.z, v.w};
#pragma unroll
    for (int j = 0; j < 4; j++) {
      float xv = vv[j];
      const float4 r0 = *(const float4*)(rw + (d + j) * 8);
      const float4 r1 = *(const float4*)(rw + (d + j) * 8 + 4);
      acc[0] += xv * r0.x; acc[1] += xv * r0.y;
      acc[2] += xv * r0.z; acc[3] += xv * r0.w;
      acc[4] += xv * r1.x; acc[5] += xv * r1.y;
      acc[6] += xv * r1.z; acc[7] += xv * r1.w;
    }
  }
#pragma unroll
  for (int e = 0; e < 8; e++) {
    float v = acc[e];
#pragma unroll
    for (int off = 32; off > 0; off >>= 1) v += __shfl_xor(v, off, 64);
    acc[e] = v;     // all lanes now hold the full logit
  }
  float tclamp = fminf(fmaxf(temp[0], 0.1f), 5.0f);
  float invt = 1.0f / tclamp;
  float mx = -1e30f;
#pragma unroll
  for (int e = 0; e < 8; e++) { acc[e] *= invt; mx = fmaxf(mx, acc[e]); }
  float p[8]; float s = 0.f;
#pragma unroll
  for (int e = 0; e < 8; e++) { p[e] = __expf(acc[e] - mx); s += p[e]; }
  float invs = 1.0f / s;
  float ent = 0.f;
#pragma unroll
  for (int e = 0; e < 8; e++) {
    p[e] *= invs;
    ent -= p[e] * __logf(fmaxf(p[e], 1e-8f));
  }
  // top-2, ties -> lowest index (matches jax top_k)
  int i1 = 0; float w1 = p[0];
#pragma unroll
  for (int e = 1; e < 8; e++) if (p[e] > w1) { w1 = p[e]; i1 = e; }
  int i2 = (i1 == 0) ? 1 : 0; float w2 = p[i2];
#pragma unroll
  for (int e = 0; e < 8; e++) if (e != i1 && p[e] > w2) { w2 = p[e]; i2 = e; }

  __shared__ float s_imp[4][8];
  __shared__ float s_ent[4];
  if (lane == 0) {
    int pos1 = atomicAdd(&cnt[i1], 1);
    rowtok[i1 * T_TOK + pos1] = t * 2;        // hid row index = t*2 + slot
    rowwt [i1 * T_TOK + pos1] = w1;
    int pos2 = atomicAdd(&cnt[i2], 1);
    rowtok[i2 * T_TOK + pos2] = t * 2 + 1;
    rowwt [i2 * T_TOK + pos2] = w2;
#pragma unroll
    for (int e = 0; e < 8; e++) s_imp[wid][e] = p[e];
    s_ent[wid] = ent;
  }
  __syncthreads();
  if (threadIdx.x < 8) {
    int e = threadIdx.x;
    imp_part[blockIdx.x * 8 + e] =
        s_imp[0][e] + s_imp[1][e] + s_imp[2][e] + s_imp[3][e];
  } else if (threadIdx.x == 8) {
    ent_part[blockIdx.x] = s_ent[0] + s_ent[1] + s_ent[2] + s_ent[3];
  }
}

// ---------------- aux losses + GEMM tile schedule ---------------------------
__global__ __launch_bounds__(256) void aux_final_kernel(
    const float* __restrict__ imp_part, const float* __restrict__ ent_part,
    const int* __restrict__ cnt, int* __restrict__ tileoff,
    float* __restrict__ out_aux)
{
  __shared__ float simp[256];
  __shared__ float sent[256];
  int tid = threadIdx.x;
  int e = tid & 7, g = tid >> 3;
  float ia = 0.f;
  for (int b = g; b < 2048; b += 32) ia += imp_part[b * 8 + e];
  simp[tid] = ia;
  float ea = 0.f;
  for (int b = tid; b < 2048; b += 256) ea += ent_part[b];
  sent[tid] = ea;
  __syncthreads();
  if (tid == 0) {
    float imp[8] = {0,0,0,0,0,0,0,0};
    float ent = 0.f;
    for (int i = 0; i < 256; i++) { imp[i & 7] += simp[i]; ent += sent[i]; }
    float aux = 0.f;
    for (int ee = 0; ee < 8; ee++) {
      float importance = imp[ee] / 8192.0f;
      float load = (float)cnt[ee] / (8192.0f + 1e-6f);
      aux += importance * load;
    }
    out_aux[0] = aux * 8.0f * 0.01f;
    out_aux[1] = (ent / 8192.0f) * 0.01f;
    out_aux[2] = 0.f;
    int off = 0;
    for (int ee = 0; ee < 8; ee++) { tileoff[ee] = off; off += (cnt[ee] + 127) >> 7; }
    tileoff[8] = off;
  }
}

// ---------------- fused vectorized transpose+cast of all weights ------------
// z<16: Wg/Wu (e=z>>1, up=z&1): src [D][H] fp32 -> BguT[e][n'][d] bf16,
//       n' = (h>>5)*64 + (h&31) + up*32  (granularity-32 gate/up interleave)
// z>=16: Wd (e=z-16): src [H][D] fp32 -> BdT[e][d][h] bf16 (plain transpose)
__global__ __launch_bounds__(256) void transpose_all_kernel(
    const float* __restrict__ Wg, const float* __restrict__ Wu,
    const float* __restrict__ Wd,
    __bf16* __restrict__ BguT, __bf16* __restrict__ BdT)
{
  __shared__ float tile[64 * 129];
  int z = blockIdx.z;
  const float* src; __bf16* dst;
  int C, Kd, r0, c0, up = 0;
  bool gu = z < 16;
  if (gu) {
    int e = z >> 1; up = z & 1;
    src = (up ? Wu : Wg) + (size_t)e * D_DIM * H_DIM;
    dst = BguT + (size_t)e * NGU * D_DIM;
    C = H_DIM; Kd = D_DIM;
    c0 = (blockIdx.x & 31) << 7;  r0 = (blockIdx.x >> 5) << 6;
  } else {
    int e = z - 16;
    src = Wd + (size_t)e * H_DIM * D_DIM;
    dst = BdT + (size_t)e * D_DIM * H_DIM;
    C = D_DIM; Kd = H_DIM;
    c0 = (blockIdx.x & 7) << 7;   r0 = (blockIdx.x >> 3) << 6;
  }
  int t = threadIdx.x;
  int cq = t & 31, rb = t >> 5;
#pragma unroll
  for (int i = 0; i < 8; i++) {
    int r = rb + 8 * i;
    float4 v = *(const float4*)(src + (size_t)(r0 + r) * C + c0 + cq * 4);
    *(float4*)&tile[r * 129 + cq * 4] = v;
  }
  __syncthreads();
#pragma unroll
  for (int i = 0; i < 4; i++) {
    int c = t + (i << 8);         // chunk id 0..1023
    int hl = c >> 3;              // dst-row local (src-col local) 0..127
    int rc = c & 7;               // 8-elem k-chunk within dst row
    int dstrow;
    if (gu) { int h = c0 + hl; dstrow = ((h >> 5) << 6) + (h & 31) + (up << 5); }
    else    { dstrow = c0 + hl; }
    bf16x8 o;
#pragma unroll
    for (int j = 0; j < 8; j++)
      o[j] = (__bf16)tile[(rc * 8 + j) * 129 + hl];
    *(bf16x8*)(dst + (size_t)dstrow * Kd + r0 + rc * 8) = o;
  }
}

// ---------------- GEMM1: gathered x @ BguT[e], fused SwiGLU, scaled by we ---
// 128x128 tile, BK=64, 32x32x16 bf16 MFMA, XOR-swizzled LDS.
// Wave w: rows [wm*64, +64), cols [wn*64, +64); 2x2 MFMA blocks of 32.
// C/D: col=lane&31, row=(reg&3)+8*(reg>>2)+4*(lane>>5)  [m74/m101]
__global__ __launch_bounds__(256, 2) void gemm1_kernel(
    const __bf16* __restrict__ xb, const __bf16* __restrict__ BguT,
    const int* __restrict__ rowtok, const float* __restrict__ rowwt,
    const int* __restrict__ cnt, const int* __restrict__ tileoff,
    __bf16* __restrict__ hid)
{
  __shared__ __bf16 As[128 * 64];
  __shared__ __bf16 Bs[128 * 64];
  __shared__ int   s_tok[128];
  __shared__ float s_wt[128];

  int y = blockIdx.y;
  if (y >= tileoff[8]) return;
  int e = 0;
  while (y >= tileoff[e + 1]) e++;
  int m0 = (y - tileoff[e]) << 7;
  int cntE = cnt[e];
  int tid = threadIdx.x;
  if (tid < 128) {
    int m = m0 + tid;
    bool v = m < cntE;
    s_tok[tid] = v ? rowtok[e * T_TOK + m] : 0;
    s_wt [tid] = v ? rowwt [e * T_TOK + m] : 0.f;
  }
  __syncthreads();

  const int n0 = blockIdx.x << 7;
  const __bf16* Bp = BguT + (size_t)e * NGU * D_DIM;
  const int lane = tid & 63;
  const int wid = tid >> 6;
  const int wm = wid >> 1, wn = wid & 1;
  const int l31 = lane & 31, l1 = lane >> 5;

  f32x16 acc[2][2];
#pragma unroll
  for (int a = 0; a < 2; a++)
#pragma unroll
    for (int b = 0; b < 2; b++) acc[a][b] = (f32x16)(0.f);

  int q[4], ar[4], akc[4];
#pragma unroll
  for (int c = 0; c < 4; c++) {
    q[c]   = tid + (c << 8);
    ar[c]  = q[c] >> 3;
    akc[c] = ((q[c] & 7) ^ (ar[c] & 7)) << 3;   // XOR swizzle on global side
  }

  for (int kt = 0; kt < 16; kt++) {
    int k0 = kt << 6;
#pragma unroll
    for (int c = 0; c < 4; c++) {
      const __bf16* ga = xb + (size_t)(s_tok[ar[c]] >> 1) * D_DIM + (k0 + akc[c]);
      gl_lds16(ga, &As[q[c] << 3]);
    }
#pragma unroll
    for (int c = 0; c < 4; c++) {
      const __bf16* gb = Bp + (size_t)(n0 + ar[c]) * D_DIM + (k0 + akc[c]);
      gl_lds16(gb, &Bs[q[c] << 3]);
    }
    __syncthreads();
#pragma unroll
    for (int ks = 0; ks < 4; ks++) {          // k16 steps within BK=64
      bf16x8 af[2], bfv[2];
      int cch = ks * 2 + l1;                   // logical 8-elem chunk
#pragma unroll
      for (int mi = 0; mi < 2; mi++) {
        int row = wm * 64 + mi * 32 + l31;
        af[mi] = *(const bf16x8*)&As[(row * 8 + (cch ^ (row & 7))) * 8];
      }
#pragma unroll
      for (int ni = 0; ni < 2; ni++) {
        int row = wn * 64 + ni * 32 + l31;
        bfv[ni] = *(const bf16x8*)&Bs[(row * 8 + (cch ^ (row & 7))) * 8];
      }
#pragma unroll
      for (int mi = 0; mi < 2; mi++)
#pragma unroll
        for (int ni = 0; ni < 2; ni++)
          acc[mi][ni] = __builtin_amdgcn_mfma_f32_32x32x16_bf16(
              af[mi], bfv[ni], acc[mi][ni], 0, 0, 0);
    }
    __syncthreads();
  }

  // SwiGLU epilogue: ni=0 is gate cols, ni=1 is up cols (granularity-32
  // interleave), identical lane->col mapping -> pure register math.
  int h = (((n0 + wn * 64) >> 6) << 5) + l31;
#pragma unroll
  for (int mi = 0; mi < 2; mi++) {
    f32x16 gt = acc[mi][0];
    f32x16 up = acc[mi][1];
#pragma unroll
    for (int r = 0; r < 16; r++) {
      int rl = wm * 64 + mi * 32 + (r & 3) + ((r >> 2) << 3) + (l1 << 2);
      if (m0 + rl < cntE) {
        float u = up[r];
        float hv = (u / (1.f + __expf(-u))) * gt[r] * s_wt[rl];
        hid[(size_t)s_tok[rl] * H_DIM + h] = (__bf16)hv;
      }
    }
  }
}

// ---------------- GEMM2: hid @ BdT[e], direct store into ytmp[2T][D] --------
__global__ __launch_bounds__(256, 2) void gemm2_kernel(
    const __bf16* __restrict__ hid, const __bf16* __restrict__ BdT,
    const int* __restrict__ rowtok, const int* __restrict__ cnt,
    const int* __restrict__ tileoff, float* __restrict__ ytmp)
{
  __shared__ __bf16 As[128 * 64];
  __shared__ __bf16 Bs[128 * 64];
  __shared__ int s_tok[128];

  int y = blockIdx.y;
  if (y >= tileoff[8]) return;
  int e = 0;
  while (y >= tileoff[e + 1]) e++;
  int m0 = (y - tileoff[e]) << 7;
  int cntE = cnt[e];
  int tid = threadIdx.x;
  if (tid < 128) {
    int m = m0 + tid;
    s_tok[tid] = (m < cntE) ? rowtok[e * T_TOK + m] : 0;
  }
  __syncthreads();

  const int n0 = blockIdx.x << 7;
  const __bf16* Bp = BdT + (size_t)e * D_DIM * H_DIM;
  const int lane = tid & 63;
  const int wid = tid >> 6;
  const int wm = wid >> 1, wn = wid & 1;
  const int l31 = lane & 31, l1 = lane >> 5;

  f32x16 acc[2][2];
#pragma unroll
  for (int a = 0; a < 2; a++)
#pragma unroll
    for (int b = 0; b < 2; b++) acc[a][b] = (f32x16)(0.f);

  int q[4], ar[4], akc[4];
#pragma unroll
  for (int c = 0; c < 4; c++) {
    q[c]   = tid + (c << 8);
    ar[c]  = q[c] >> 3;
    akc[c] = ((q[c] & 7) ^ (ar[c] & 7)) << 3;
  }

  for (int kt = 0; kt < 64; kt++) {
    int k0 = kt << 6;
#pragma unroll
    for (int c = 0; c < 4; c++) {
      const __bf16* ga = hid + (size_t)s_tok[ar[c]] * H_DIM + (k0 + akc[c]);
      gl_lds16(ga, &As[q[c] << 3]);
    }
#pragma unroll
    for (int c = 0; c < 4; c++) {
      const __bf16* gb = Bp + (size_t)(n0 + ar[c]) * H_DIM + (k0 + akc[c]);
      gl_lds16(gb, &Bs[q[c] << 3]);
    }
    __syncthreads();
#pragma unroll
    for (int ks = 0; ks < 4; ks++) {
      bf16x8 af[2], bfv[2];
      int cch = ks * 2 + l1;
#pragma unroll
      for (int mi = 0; mi < 2; mi++) {
        int row = wm * 64 + mi * 32 + l31;
        af[mi] = *(const bf16x8*)&As[(row * 8 + (cch ^ (row & 7))) * 8];
      }
#pragma unroll
      for (int ni = 0; ni < 2; ni++) {
        int row = wn * 64 + ni * 32 + l31;
        bfv[ni] = *(const bf16x8*)&Bs[(row * 8 + (cch ^ (row & 7))) * 8];
      }
#pragma unroll
      for (int mi = 0; mi < 2; mi++)
#pragma unroll
        for (int ni = 0; ni < 2; ni++)
          acc[mi][ni] = __builtin_amdgcn_mfma_f32_32x32x16_bf16(
              af[mi], bfv[ni], acc[mi][ni], 0, 0, 0);
    }
    __syncthreads();
  }

#pragma unroll
  for (int mi = 0; mi < 2; mi++)
#pragma unroll
    for (int ni = 0; ni < 2; ni++) {
      int coln = n0 + wn * 64 + ni * 32 + l31;
#pragma unroll
      for (int r = 0; r < 16; r++) {
        int rl = wm * 64 + mi * 32 + (r & 3) + ((r >> 2) << 3) + (l1 << 2);
        if (m0 + rl < cntE)
          ytmp[(size_t)s_tok[rl] * D_DIM + coln] = acc[mi][ni][r];
      }
    }
}

// ---------------- combine: out[t] = ytmp[2t] + ytmp[2t+1] -------------------
__global__ __launch_bounds__(256) void combine_kernel(
    const float* __restrict__ ytmp, float* __restrict__ out)
{
  size_t i = ((size_t)blockIdx.x * 256 + threadIdx.x) * 4;
  size_t t = i >> 10;            // D=1024
  size_t col = i & 1023;
  const float4 a = *(const float4*)(ytmp + ((t * 2) << 10) + col);
  const float4 b = *(const float4*)(ytmp + ((t * 2 + 1) << 10) + col);
  float4 o = {a.x + b.x, a.y + b.y, a.z + b.z, a.w + b.w};
  *(float4*)(out + i) = o;
}

// ---------------- launch ----------------------------------------------------
extern "C" void kernel_launch(void* const* d_in, const int* in_sizes, int n_in,
                              void* d_out, int out_size, void* d_ws, size_t ws_size,
                              hipStream_t stream)
{
  const float* x    = (const float*)d_in[0];
  const float* rw   = (const float*)d_in[1];
  const float* temp = (const float*)d_in[2];
  const float* Wg   = (const float*)d_in[3];
  const float* Wu   = (const float*)d_in[4];
  const float* Wd   = (const float*)d_in[5];
  float* out = (float*)d_out;

  char* ws = (char*)d_ws;
  size_t off = 0;
  auto alloc = [&](size_t bytes) -> void* {
    void* p = ws + off;
    off = (off + bytes + 255) & ~(size_t)255;
    return p;
  };
  __bf16* xb     = (__bf16*)alloc((size_t)T_TOK * D_DIM * 2);
  __bf16* BguT   = (__bf16*)alloc((size_t)NEXP * NGU * D_DIM * 2);
  __bf16* BdT    = (__bf16*)alloc((size_t)NEXP * D_DIM * H_DIM * 2);
  __bf16* hid    = (__bf16*)alloc((size_t)T_TOK * 2 * H_DIM * 2);
  int*    rowtok = (int*)  alloc((size_t)NEXP * T_TOK * 4);
  float*  rowwt  = (float*)alloc((size_t)NEXP * T_TOK * 4);
  int*    cnt    = (int*)  alloc(64);
  int*    tileoff= (int*)  alloc(64);
  float*  imp_part = (float*)alloc(2048 * 8 * 4);
  float*  ent_part = (float*)alloc(2048 * 4);
  // ytmp (67 MB) aliases BguT (134 MB): BguT is dead after gemm1 completes,
  // gemm2 (stream-ordered after) writes ytmp, combine reads it.
  float* ytmp = (float*)BguT;
  (void)ws_size; (void)n_in; (void)in_sizes;

  hipMemsetAsync(cnt, 0, 64, stream);

  router_kernel<<<2048, 256, 0, stream>>>(x, rw, temp, xb, rowtok, rowwt, cnt,
                                          imp_part, ent_part);
  aux_final_kernel<<<1, 256, 0, stream>>>(imp_part, ent_part, cnt, tileoff,
                                          out + (size_t)T_TOK * D_DIM);
  transpose_all_kernel<<<dim3(512, 1, 24), 256, 0, stream>>>(Wg, Wu, Wd,
                                                             BguT, BdT);
  gemm1_kernel<<<dim3(64, MAX_YT), 256, 0, stream>>>(xb, BguT, rowtok, rowwt,
                                                     cnt, tileoff, hid);
  gemm2_kernel<<<dim3(8, MAX_YT), 256, 0, stream>>>(hid, BdT, rowtok, cnt,
                                                    tileoff, ytmp);
  combine_kernel<<<8192, 256, 0, stream>>>(ytmp, out);
}